// Round 12
// baseline (4012.330 us; speedup 1.0000x reference)
//
#include <hip/hip_runtime.h>
#include <stdint.h>

#define T_STEPS 2048
#define NBATCH  64
#define DIN     256
#define HID     512
#define NCOL    2048     // 4*HID
#define LDK     776      // z row stride (bf16): 1552 B, 16B-aligned rows (proven)
#define NGRP    8        // groups (blockIdx & 7)
#define BPG     32       // blocks per group (j-slices of 16)
#define MROW    8        // batches per group
#define SENT    0xFFFFFFFFu   // impossible packed-bf16-pair for h in (-1,1)

#define HBUF_DWORDS ((size_t)4 * NBATCH * (HID / 2))   // quad-buffered h exchange

typedef __attribute__((ext_vector_type(8))) short bf16x8;
typedef __attribute__((ext_vector_type(4))) float f32x4;

static __device__ __forceinline__ ushort f2bf(float f) {
    union { float f; uint32_t u; } v; v.f = f;
    uint32_t r = v.u + 0x7FFFu + ((v.u >> 16) & 1u);   // RNE
    return (ushort)(r >> 16);
}
static __device__ __forceinline__ float sigm(float x) { return 1.f / (1.f + __expf(-x)); }
static __device__ __forceinline__ float tanh_fast(float x) {
    float a = fabsf(x);
    float e = __expf(-2.f * a);
    float t = (1.f - e) / (1.f + e);
    return x < 0.f ? -t : t;
}
// compiler-legal coherent poll load (R2-proven path); u64 = 2 packed bf16 pairs
static __device__ __forceinline__ unsigned long long ldq(const unsigned long long* p) {
    return __hip_atomic_load(p, __ATOMIC_RELAXED, __HIP_MEMORY_SCOPE_AGENT);
}
static __device__ __forceinline__ bool chk64(unsigned long long v) {
    return ((uint32_t)v != SENT) && ((uint32_t)(v >> 32) != SENT);
}

__global__ void sent_fill_kernel(uint32_t* w, size_t n) {
    size_t i = (size_t)blockIdx.x * blockDim.x + threadIdx.x;
    if (i < n) w[i] = SENT;
}

__global__ __launch_bounds__(256, 1) void lstm_persist(
    const float* __restrict__ x,     // [T][B][D]
    const float* __restrict__ Wx,    // [D][4H]
    const float* __restrict__ Wh,    // [H][4H]
    const float* __restrict__ bias,  // [4H]
    float* __restrict__ out,         // ys [T][B][H] + hT [B][H] + cT [B][H]
    uint32_t* __restrict__ hbuf)     // [4][B][H/2] packed bf16 pairs, SENT-initialized
{
    __shared__ __align__(16) ushort zlds[16][LDK];   // z = [x_t ; h_t], rows 8..15 zero
    __shared__ __align__(16) float gex[8][17][4];    // [batch][j(+pad)][gate i,f,g,o]

    const int tid  = threadIdx.x;          // 256 threads = 4 waves
    const int gid  = blockIdx.x & 7;       // group
    const int p    = blockIdx.x >> 3;      // block-in-group
    const int j0   = p * 16;
    const int gb   = gid * MROW;
    const int wave = tid >> 6;             // gate index 0..3 (MFMA phase)
    const int lane = tid & 63;

    for (int i = tid; i < 8 * LDK; i += 256) zlds[8 + i / LDK][i % LDK] = 0;

    // weight slice -> registers (MFMA B layout)
    bf16x8 wreg[24];
    {
        const int col   = wave * HID + j0 + (lane & 15);
        const int kbase = (lane >> 4) * 8;
        #pragma unroll
        for (int ch = 0; ch < 24; ++ch) {
            bf16x8 w;
            #pragma unroll
            for (int e = 0; e < 8; ++e) {
                int k = ch * 32 + kbase + e;
                float wv = (k < DIN) ? Wx[(size_t)k * NCOL + col]
                                     : Wh[(size_t)(k - DIN) * NCOL + col];
                w[e] = (short)f2bf(wv);
            }
            wreg[ch] = w;
        }
    }
    const float biasv = bias[wave * HID + j0 + (lane & 15)];
    float c0 = 0.f, c1 = 0.f;               // c state: wave0, b=tid>>3, j=2*(tid&7)+{0,1}
    __syncthreads();

    const int xr   = tid >> 5;              // x staging row
    const int xc   = (tid & 31) * 8;        // 8 x-elems / thread
    const int arow = lane & 15;
    const int koff = (lane >> 4) * 8;
    const ushort* za = &zlds[arow][0];
    const int hr = wave * 2;                // h rows: hr, hr+1 (lane-consecutive dwords)

    // x_0 into registers (plain loads; compiler manages the wait)
    float4 xa, xb;
    {
        const float* xp = x + ((size_t)0 * NBATCH + gb + xr) * DIN + xc;
        xa = *(const float4*)xp;
        xb = *(const float4*)(xp + 4);
    }

    for (int t = 0; t < T_STEPS; ++t) {
        // pack x_t (bf16) -> LDS (values already in registers, compiler-waited)
        {
            uint4 pk;
            pk.x = (uint32_t)f2bf(xa.x) | ((uint32_t)f2bf(xa.y) << 16);
            pk.y = (uint32_t)f2bf(xa.z) | ((uint32_t)f2bf(xa.w) << 16);
            pk.z = (uint32_t)f2bf(xb.x) | ((uint32_t)f2bf(xb.y) << 16);
            pk.w = (uint32_t)f2bf(xb.z) | ((uint32_t)f2bf(xb.w) << 16);
            *(uint4*)&zlds[xr][xc] = pk;
        }
        __syncthreads();                                   // bar1

        // poll round-0 issue (data IS the flag). Placed before the MFMAs so the
        // compiler schedules the loads early and waits only at the check.
        const unsigned long long* hq =
            (const unsigned long long*)(hbuf + ((size_t)(t & 3) * NBATCH + gb + hr) * (HID / 2))
            + 2 * lane;
        const unsigned long long* hq2 = hq + (HID / 4);    // next row (+256 dwords)
        unsigned long long pa0 = 0, pa1 = 0, pb0 = 0, pb1 = 0;
        if (t > 0) {
            pa0 = ldq(hq);  pa1 = ldq(hq + 1);
            pb0 = ldq(hq2); pb1 = ldq(hq2 + 1);
        }

        // x prefetch for t+1 (plain loads; drain at bar3, hidden under poll+MFMA)
        {
            int tn = (t + 1 < T_STEPS) ? t + 1 : t;
            const float* xp = x + ((size_t)tn * NBATCH + gb + xr) * DIN + xc;
            xa = *(const float4*)xp;
            xb = *(const float4*)(xp + 4);
        }

        // x-part MFMAs (K = 0..255)
        f32x4 a0 = {0.f, 0.f, 0.f, 0.f};
        #pragma unroll
        for (int ch = 0; ch < 8; ++ch) {
            bf16x8 af = *(const bf16x8*)(za + ch * 32 + koff);
            a0 = __builtin_amdgcn_mfma_f32_16x16x32_bf16(af, wreg[ch], a0, 0, 0, 0);
        }

        // poll loop: all values compiler-tracked (no in-flight register reads)
        if (t > 0) {
            int guard = 0;
            while (true) {
                bool ok = chk64(pa0) && chk64(pa1) && chk64(pb0) && chk64(pb1);
                if (__all((int)ok)) break;
                if (++guard > (1 << 17)) break;            // hang safety
                pa0 = ldq(hq);  pa1 = ldq(hq + 1);
                pb0 = ldq(hq2); pb1 = ldq(hq2 + 1);
            }
            uint4 q0, q1;
            q0.x = (uint32_t)pa0; q0.y = (uint32_t)(pa0 >> 32);
            q0.z = (uint32_t)pa1; q0.w = (uint32_t)(pa1 >> 32);
            q1.x = (uint32_t)pb0; q1.y = (uint32_t)(pb0 >> 32);
            q1.z = (uint32_t)pb1; q1.w = (uint32_t)(pb1 >> 32);
            *(uint4*)&zlds[hr][DIN + 8 * lane]     = q0;
            *(uint4*)&zlds[hr + 1][DIN + 8 * lane] = q1;
        } else {
            uint4 z4 = {0u, 0u, 0u, 0u};                   // h_0 = 0
            *(uint4*)&zlds[hr][DIN + 8 * lane]     = z4;
            *(uint4*)&zlds[hr + 1][DIN + 8 * lane] = z4;
        }

        // wave0 sentinel reset of buf[(t+2)&3] (drained by bar3's full vmcnt(0),
        // hence performed before this step's publish — release-chain preserved)
        if (tid < 64) {
            const int b = tid >> 3, jp = tid & 7;
            __hip_atomic_store(hbuf + ((size_t)((t + 2) & 3) * NBATCH + gb + b) * (HID / 2)
                               + (j0 >> 1) + jp, SENT,
                               __ATOMIC_RELAXED, __HIP_MEMORY_SCOPE_AGENT);
        }
        __syncthreads();                                   // bar3: hlds + reset drained

        // h-part MFMAs (K = 256..767), four chains
        f32x4 a1 = {0.f, 0.f, 0.f, 0.f};
        f32x4 a2 = {0.f, 0.f, 0.f, 0.f};
        f32x4 a3 = {0.f, 0.f, 0.f, 0.f};
        f32x4 a4 = {0.f, 0.f, 0.f, 0.f};
        #pragma unroll
        for (int ch = 8; ch < 12; ++ch) {
            bf16x8 af = *(const bf16x8*)(za + ch * 32 + koff);
            a1 = __builtin_amdgcn_mfma_f32_16x16x32_bf16(af, wreg[ch], a1, 0, 0, 0);
        }
        #pragma unroll
        for (int ch = 12; ch < 16; ++ch) {
            bf16x8 af = *(const bf16x8*)(za + ch * 32 + koff);
            a2 = __builtin_amdgcn_mfma_f32_16x16x32_bf16(af, wreg[ch], a2, 0, 0, 0);
        }
        #pragma unroll
        for (int ch = 16; ch < 20; ++ch) {
            bf16x8 af = *(const bf16x8*)(za + ch * 32 + koff);
            a3 = __builtin_amdgcn_mfma_f32_16x16x32_bf16(af, wreg[ch], a3, 0, 0, 0);
        }
        #pragma unroll
        for (int ch = 20; ch < 24; ++ch) {
            bf16x8 af = *(const bf16x8*)(za + ch * 32 + koff);
            a4 = __builtin_amdgcn_mfma_f32_16x16x32_bf16(af, wreg[ch], a4, 0, 0, 0);
        }
        f32x4 acc = ((a0 + a1) + (a2 + a3)) + a4;

        // gate exchange: acc row=(lane>>4)*4+r (batch), col=lane&15 (j)
        if (lane < 32) {
            int r0 = (lane >> 4) * 4, col = lane & 15;
            #pragma unroll
            for (int r = 0; r < 4; ++r)
                gex[r0 + r][col][wave] = acc[r] + biasv;
        }
        __syncthreads();                                   // bar4

        // wave0 cell update + publish (reset already performed before bar3)
        if (tid < 64) {
            const int b = tid >> 3, jp = tid & 7, j = jp * 2;
            f32x4 ga = *(const f32x4*)&gex[b][j][0];
            f32x4 gc = *(const f32x4*)&gex[b][j + 1][0];
            float i0 = sigm(ga[0]), f0 = sigm(ga[1]), g0 = tanh_fast(ga[2]), o0 = sigm(ga[3]);
            float i1 = sigm(gc[0]), f1 = sigm(gc[1]), g1 = tanh_fast(gc[2]), o1 = sigm(gc[3]);
            c0 = f0 * c0 + i0 * g0;
            c1 = f1 * c1 + i1 * g1;
            float h0v = o0 * tanh_fast(c0);
            float h1v = o1 * tanh_fast(c1);

            uint32_t pkh = (uint32_t)f2bf(h0v) | ((uint32_t)f2bf(h1v) << 16);
            __hip_atomic_store(hbuf + ((size_t)((t + 1) & 3) * NBATCH + gb + b) * (HID / 2)
                               + (j0 >> 1) + jp, pkh,
                               __ATOMIC_RELAXED, __HIP_MEMORY_SCOPE_AGENT);

            float2 hv = {h0v, h1v};
            *(float2*)(out + ((size_t)t * NBATCH + gb + b) * HID + j0 + j) = hv;
            if (t == T_STEPS - 1) {
                float* hTp = out + (size_t)T_STEPS * NBATCH * HID
                             + (size_t)(gb + b) * HID + j0 + j;
                float2 cv = {c0, c1};
                *(float2*)hTp = hv;
                *(float2*)(hTp + (size_t)NBATCH * HID) = cv;
            }
        }
        // no trailing barrier: bar1 re-syncs
    }
}

extern "C" void kernel_launch(void* const* d_in, const int* in_sizes, int n_in,
                              void* d_out, int out_size, void* d_ws, size_t ws_size,
                              hipStream_t stream) {
    const float* x    = (const float*)d_in[0];
    const float* Wx   = (const float*)d_in[1];
    const float* Wh   = (const float*)d_in[2];
    const float* bias = (const float*)d_in[3];
    float* out = (float*)d_out;

    uint32_t* hbuf = (uint32_t*)d_ws;                  // [4][64][256] dwords = 256 KB

    {
        size_t n = HBUF_DWORDS;
        int blocks = (int)((n + 255) / 256);
        sent_fill_kernel<<<dim3(blocks), dim3(256), 0, stream>>>(hbuf, n);
    }
    lstm_persist<<<dim3(NGRP * BPG), dim3(256), 0, stream>>>(x, Wx, Wh, bias, out, hbuf);
}